// Round 1
// baseline (6056.253 us; speedup 1.0000x reference)
//
#include <hip/hip_runtime.h>

#define N_TOT 10000
#define CLS_P 1000
#define NC 10
#define D 1024

#define BI 64
#define BJ 64
#define JCH 640
#define KC 16

// ---------------- zero output ----------------
__global__ void zero_kernel(int* __restrict__ out, int n) {
    int i = blockIdx.x * blockDim.x + threadIdx.x;
    if (i < n) out[i] = 0;
}

// ---------------- fp64 squared norms ----------------
__global__ void sq_kernel(const float* __restrict__ feats, const int* __restrict__ ids,
                          double* __restrict__ sqd) {
    int row = blockIdx.x;
    int id = ids[row];
    const float4* rp = (const float4*)(feats + (size_t)id * D);
    float4 v = rp[threadIdx.x];  // 256 threads * 4 floats = 1024
    double s = (double)v.x * v.x + (double)v.y * v.y + (double)v.z * v.z + (double)v.w * v.w;
    #pragma unroll
    for (int off = 32; off > 0; off >>= 1)
        s += __shfl_down(s, off, 64);
    __shared__ double wsum[4];
    int lane = threadIdx.x & 63, wv = threadIdx.x >> 6;
    if (lane == 0) wsum[wv] = s;
    __syncthreads();
    if (threadIdx.x == 0)
        sqd[row] = wsum[0] + wsum[1] + wsum[2] + wsum[3];
}

// ---------------- fp64 pairwise count ----------------
__launch_bounds__(256)
__global__ void count_kernel(const float* __restrict__ feats, const int* __restrict__ ids,
                             const double* __restrict__ sqd, int* __restrict__ counts) {
    __shared__ double Ad[KC][BI];
    __shared__ double Bd[KC][BJ];
    __shared__ int cred[BI];

    const int tid = threadIdx.x;
    const int ti = tid & 15;        // i-group 0..15
    const int tj = tid >> 4;        // j-group 0..15
    const int i_base = blockIdx.x * BI;
    const int j_base0 = blockIdx.y * JCH;

    // staging mapping: one float4 per thread per tile
    const int s_row = tid >> 2;         // 0..63
    const int s_kq  = (tid & 3) * 4;    // 0,4,8,12

    int cnt[4] = {0, 0, 0, 0};

    double sqi[4];
    int clsi[4], ivalid[4];
    #pragma unroll
    for (int ii = 0; ii < 4; ii++) {
        int i = i_base + 4 * ti + ii;
        ivalid[ii] = (i < N_TOT);
        sqi[ii] = ivalid[ii] ? sqd[i] : 0.0;
        clsi[ii] = i / CLS_P;
    }

    for (int jt = 0; jt < JCH / BJ; jt++) {
        const int j_base = j_base0 + jt * BJ;
        if (j_base >= N_TOT) break;  // uniform across block

        double acc[4][4];
        #pragma unroll
        for (int ii = 0; ii < 4; ii++)
            #pragma unroll
            for (int jj = 0; jj < 4; jj++)
                acc[ii][jj] = 0.0;

        for (int kc = 0; kc < D / KC; kc++) {
            __syncthreads();
            // stage A tile (fp32 -> fp64)
            {
                int gi = i_base + s_row;
                float4 v = make_float4(0.f, 0.f, 0.f, 0.f);
                if (gi < N_TOT)
                    v = *(const float4*)(feats + (size_t)ids[gi] * D + kc * KC + s_kq);
                Ad[s_kq + 0][s_row] = (double)v.x;
                Ad[s_kq + 1][s_row] = (double)v.y;
                Ad[s_kq + 2][s_row] = (double)v.z;
                Ad[s_kq + 3][s_row] = (double)v.w;
            }
            // stage B tile
            {
                int gj = j_base + s_row;
                float4 v = make_float4(0.f, 0.f, 0.f, 0.f);
                if (gj < N_TOT)
                    v = *(const float4*)(feats + (size_t)ids[gj] * D + kc * KC + s_kq);
                Bd[s_kq + 0][s_row] = (double)v.x;
                Bd[s_kq + 1][s_row] = (double)v.y;
                Bd[s_kq + 2][s_row] = (double)v.z;
                Bd[s_kq + 3][s_row] = (double)v.w;
            }
            __syncthreads();

            #pragma unroll
            for (int k = 0; k < KC; k++) {
                const double2* ap = (const double2*)&Ad[k][4 * ti];
                const double2* bp = (const double2*)&Bd[k][4 * tj];
                double2 a01 = ap[0], a23 = ap[1];
                double2 b01 = bp[0], b23 = bp[1];
                double a[4] = {a01.x, a01.y, a23.x, a23.y};
                double b[4] = {b01.x, b01.y, b23.x, b23.y};
                #pragma unroll
                for (int ii = 0; ii < 4; ii++)
                    #pragma unroll
                    for (int jj = 0; jj < 4; jj++)
                        acc[ii][jj] += a[ii] * b[jj];
            }
        }

        // evaluate this 64x64 tile
        #pragma unroll
        for (int jj = 0; jj < 4; jj++) {
            int j = j_base + 4 * tj + jj;
            if (j >= N_TOT) continue;
            int clsj = j / CLS_P;
            double sqj = sqd[j];
            #pragma unroll
            for (int ii = 0; ii < 4; ii++) {
                if (ivalid[ii] && clsj != clsi[ii]) {
                    double d2 = sqi[ii] + sqj - 2.0 * acc[ii][jj];
                    if (d2 < 0.25) cnt[ii]++;
                }
            }
        }
    }

    // per-block reduction over the 16 j-groups sharing each i
    if (tid < BI) cred[tid] = 0;
    __syncthreads();
    #pragma unroll
    for (int ii = 0; ii < 4; ii++)
        atomicAdd(&cred[4 * ti + ii], cnt[ii]);
    __syncthreads();
    if (tid < BI) {
        int i = i_base + tid;
        if (i < N_TOT && cred[tid] != 0)
            atomicAdd(&counts[i], cred[tid]);
    }
}

// ---------------- stable-argsort selection ----------------
__global__ void sel_kernel(const int* __restrict__ counts, const int* __restrict__ ids,
                           int* __restrict__ out_ids, int pcb) {
    int c = blockIdx.x;
    __shared__ int lc[CLS_P];
    for (int p = threadIdx.x; p < CLS_P; p += blockDim.x)
        lc[p] = counts[c * CLS_P + p];
    __syncthreads();
    for (int p = threadIdx.x; p < CLS_P; p += blockDim.x) {
        int cp = lc[p];
        int rank = 0;
        for (int q = 0; q < CLS_P; q++) {
            int cq = lc[q];
            rank += (cq < cp) || (cq == cp && q < p);
        }
        if (rank < pcb)
            out_ids[c * pcb + rank] = ids[c * CLS_P + p];
    }
}

extern "C" void kernel_launch(void* const* d_in, const int* in_sizes, int n_in,
                              void* d_out, int out_size, void* d_ws, size_t ws_size,
                              hipStream_t stream) {
    const float* feats = (const float*)d_in[0];
    const int* ids = (const int*)d_in[1];
    // budget = out_size - N_TOT (ids_selected occupies `budget` slots)
    int budget = out_size - N_TOT;
    int pcb = budget / NC;  // 200
    int* out = (int*)d_out;
    int* counts_out = out + NC * pcb;
    double* sqd = (double*)d_ws;  // 10000 doubles = 80 KB

    zero_kernel<<<(out_size + 255) / 256, 256, 0, stream>>>(out, out_size);
    sq_kernel<<<N_TOT, 256, 0, stream>>>(feats, ids, sqd);
    dim3 grid((N_TOT + BI - 1) / BI, (N_TOT + JCH - 1) / JCH);
    count_kernel<<<grid, 256, 0, stream>>>(feats, ids, sqd, counts_out);
    sel_kernel<<<NC, 256, 0, stream>>>(counts_out, ids, out, pcb);
}

// Round 2
// 1976.521 us; speedup vs baseline: 3.0641x; 3.0641x over previous
//
#include <hip/hip_runtime.h>

#define N_TOT 10000
#define CLS_P 1000
#define NC 10
#define D 1024

#define TM 128          // block tile (i and j)
#define LDT 40          // LDS row stride in bf16 elems (32 + 8 pad)
#define DELTA 2e-5f
#define ESC_CAP (1 << 22)

typedef short bf16x8 __attribute__((ext_vector_type(8)));
typedef float f32x4 __attribute__((ext_vector_type(4)));

// ---------------- zero output + escalation counter ----------------
__global__ void zero_kernel(int* __restrict__ out, int n, int* __restrict__ esc_cnt) {
    int i = blockIdx.x * blockDim.x + threadIdx.x;
    if (i < n) out[i] = 0;
    if (i == 0) *esc_cnt = 0;
}

__device__ inline unsigned short f2bf_rne(float f) {
    unsigned int u = __float_as_uint(f);
    u += 0x7fffu + ((u >> 16) & 1u);
    return (unsigned short)(u >> 16);
}
__device__ inline float bf2f(unsigned short h) {
    return __uint_as_float(((unsigned int)h) << 16);
}

// ---------------- gather + bf16 hi/lo split + fp64 norms ----------------
__global__ void prep_kernel(const float* __restrict__ feats, const int* __restrict__ ids,
                            unsigned short* __restrict__ Xhi, unsigned short* __restrict__ Xlo,
                            double* __restrict__ sqd, float* __restrict__ sqf) {
    int row = blockIdx.x;
    int id = ids[row];
    const float4* rp = (const float4*)(feats + (size_t)id * D);
    float4 v = rp[threadIdx.x];  // 256 threads * 4 = 1024
    float f[4] = {v.x, v.y, v.z, v.w};
    ushort4 hv, lv;
    unsigned short* hp = &hv.x;
    unsigned short* lp = &lv.x;
    double s = 0.0;
    #pragma unroll
    for (int e = 0; e < 4; e++) {
        s += (double)f[e] * f[e];
        unsigned short hb = f2bf_rne(f[e]);
        float lo = f[e] - bf2f(hb);        // exact
        hp[e] = hb;
        lp[e] = f2bf_rne(lo);
    }
    *(ushort4*)(Xhi + (size_t)row * D + threadIdx.x * 4) = hv;
    *(ushort4*)(Xlo + (size_t)row * D + threadIdx.x * 4) = lv;

    #pragma unroll
    for (int off = 32; off > 0; off >>= 1)
        s += __shfl_down(s, off, 64);
    __shared__ double wsum[4];
    int lane = threadIdx.x & 63, wv = threadIdx.x >> 6;
    if (lane == 0) wsum[wv] = s;
    __syncthreads();
    if (threadIdx.x == 0) {
        double t = wsum[0] + wsum[1] + wsum[2] + wsum[3];
        sqd[row] = t;
        sqf[row] = (float)t;
    }
}

// ---------------- bf16-split MFMA pairwise count ----------------
__launch_bounds__(256)
__global__ void count_kernel(const unsigned short* __restrict__ Xhi,
                             const unsigned short* __restrict__ Xlo,
                             const float* __restrict__ sqf,
                             int* __restrict__ counts,
                             int* __restrict__ esc_cnt, int2* __restrict__ esc_list) {
    __shared__ unsigned short Ah[TM * LDT], Al[TM * LDT], Bh[TM * LDT], Bl[TM * LDT];
    __shared__ int cred[TM];

    const int tid = threadIdx.x;
    const int lane = tid & 63, w = tid >> 6;
    const int wi = (w & 1) * 64, wj = (w >> 1) * 64;
    const int ib = blockIdx.x * TM, jb = blockIdx.y * TM;

    // skip tiles that are entirely same-class
    {
        int ci0 = ib / CLS_P, ci1 = (ib + TM - 1) / CLS_P;
        int cj0 = jb / CLS_P, cj1 = (jb + TM - 1) / CLS_P;
        if (ci0 == ci1 && cj0 == cj1 && ci0 == cj0) return;
    }

    f32x4 acc[4][4];
    #pragma unroll
    for (int it = 0; it < 4; it++)
        #pragma unroll
        for (int jt = 0; jt < 4; jt++)
            acc[it][jt] = (f32x4){0.f, 0.f, 0.f, 0.f};

    const int quad = lane >> 4, col = lane & 15;
    const int kq8 = quad * 8;

    for (int kc = 0; kc < D / 32; kc++) {
        __syncthreads();
        // stage 4 tiles: 128 rows x 32 k, hi+lo for A and B. 512 slots of 16B each per tile.
        #pragma unroll
        for (int rep = 0; rep < 2; rep++) {
            int s = tid + rep * 256;
            int row = s >> 2;
            int kq = (s & 3) * 8;
            size_t goff = (size_t)0 + kc * 32 + kq;
            int gi = ib + row, gj = jb + row;
            uint4 z = {0u, 0u, 0u, 0u};
            uint4 vah = (gi < N_TOT) ? *(const uint4*)(Xhi + (size_t)gi * D + goff) : z;
            uint4 val = (gi < N_TOT) ? *(const uint4*)(Xlo + (size_t)gi * D + goff) : z;
            uint4 vbh = (gj < N_TOT) ? *(const uint4*)(Xhi + (size_t)gj * D + goff) : z;
            uint4 vbl = (gj < N_TOT) ? *(const uint4*)(Xlo + (size_t)gj * D + goff) : z;
            *(uint4*)(Ah + row * LDT + kq) = vah;
            *(uint4*)(Al + row * LDT + kq) = val;
            *(uint4*)(Bh + row * LDT + kq) = vbh;
            *(uint4*)(Bl + row * LDT + kq) = vbl;
        }
        __syncthreads();

        bf16x8 ah[4], al[4], bh[4], bl[4];
        #pragma unroll
        for (int t = 0; t < 4; t++) {
            ah[t] = *(const bf16x8*)(Ah + (wi + t * 16 + col) * LDT + kq8);
            al[t] = *(const bf16x8*)(Al + (wi + t * 16 + col) * LDT + kq8);
            bh[t] = *(const bf16x8*)(Bh + (wj + t * 16 + col) * LDT + kq8);
            bl[t] = *(const bf16x8*)(Bl + (wj + t * 16 + col) * LDT + kq8);
        }
        #pragma unroll
        for (int it = 0; it < 4; it++)
            #pragma unroll
            for (int jt = 0; jt < 4; jt++) {
                acc[it][jt] = __builtin_amdgcn_mfma_f32_16x16x32_bf16(ah[it], bh[jt], acc[it][jt], 0, 0, 0);
                acc[it][jt] = __builtin_amdgcn_mfma_f32_16x16x32_bf16(al[it], bh[jt], acc[it][jt], 0, 0, 0);
                acc[it][jt] = __builtin_amdgcn_mfma_f32_16x16x32_bf16(ah[it], bl[jt], acc[it][jt], 0, 0, 0);
            }
    }

    // ---------------- epilogue: threshold + escalate + reduce ----------------
    if (tid < TM) cred[tid] = 0;
    __syncthreads();

    const float thr_lo = 0.25f - DELTA;
    const float thr_hi = 0.25f + DELTA;

    float sqj[4];
    int clsj[4], jv[4];
    #pragma unroll
    for (int jt = 0; jt < 4; jt++) {
        int j = jb + wj + jt * 16 + col;
        jv[jt] = (j < N_TOT);
        sqj[jt] = jv[jt] ? sqf[j] : 0.f;
        clsj[jt] = j / CLS_P;
    }

    #pragma unroll
    for (int it = 0; it < 4; it++) {
        #pragma unroll
        for (int r = 0; r < 4; r++) {
            int irow = wi + it * 16 + quad * 4 + r;
            int i = ib + irow;
            bool iv = (i < N_TOT);
            float sqi = iv ? sqf[i] : 0.f;
            int clsi = i / CLS_P;
            int c = 0;
            #pragma unroll
            for (int jt = 0; jt < 4; jt++) {
                if (iv && jv[jt] && clsj[jt] != clsi) {
                    float d2 = sqi + sqj[jt] - 2.0f * acc[it][jt][r];
                    if (d2 < thr_lo) {
                        c++;
                    } else if (d2 < thr_hi) {
                        int j = jb + wj + jt * 16 + col;
                        int idx = atomicAdd(esc_cnt, 1);
                        if (idx < ESC_CAP) esc_list[idx] = make_int2(i, j);
                    }
                }
            }
            // reduce across the 16 lanes of this quad (they share the same i)
            c += __shfl_xor(c, 1, 64);
            c += __shfl_xor(c, 2, 64);
            c += __shfl_xor(c, 4, 64);
            c += __shfl_xor(c, 8, 64);
            if (col == 0 && c) atomicAdd(&cred[irow], c);
        }
    }
    __syncthreads();
    if (tid < TM) {
        int i = ib + tid;
        if (i < N_TOT && cred[tid]) atomicAdd(&counts[i], cred[tid]);
    }
}

// ---------------- fp64 exact recheck of borderline pairs ----------------
__global__ void escalate_kernel(const float* __restrict__ feats, const int* __restrict__ ids,
                                const double* __restrict__ sqd,
                                const int* __restrict__ esc_cnt, const int2* __restrict__ esc_list,
                                int* __restrict__ counts) {
    int n = *esc_cnt;
    if (n > ESC_CAP) n = ESC_CAP;
    int lane = threadIdx.x & 63;
    int wglob = (blockIdx.x * blockDim.x + threadIdx.x) >> 6;
    int W = (gridDim.x * blockDim.x) >> 6;
    for (int p = wglob; p < n; p += W) {
        int2 pr = esc_list[p];
        const float* xi = feats + (size_t)ids[pr.x] * D;
        const float* xj = feats + (size_t)ids[pr.y] * D;
        double s = 0.0;
        int k0 = lane * 16;
        #pragma unroll
        for (int k = 0; k < 16; k += 4) {
            float4 a = *(const float4*)(xi + k0 + k);
            float4 b = *(const float4*)(xj + k0 + k);
            s += (double)a.x * b.x + (double)a.y * b.y + (double)a.z * b.z + (double)a.w * b.w;
        }
        #pragma unroll
        for (int off = 32; off > 0; off >>= 1)
            s += __shfl_down(s, off, 64);
        if (lane == 0) {
            double d2 = sqd[pr.x] + sqd[pr.y] - 2.0 * s;
            if (d2 < 0.25) atomicAdd(&counts[pr.x], 1);
        }
    }
}

// ---------------- stable-argsort selection ----------------
__global__ void sel_kernel(const int* __restrict__ counts, const int* __restrict__ ids,
                           int* __restrict__ out_ids, int pcb) {
    int c = blockIdx.x;
    __shared__ int lc[CLS_P];
    for (int p = threadIdx.x; p < CLS_P; p += blockDim.x)
        lc[p] = counts[c * CLS_P + p];
    __syncthreads();
    for (int p = threadIdx.x; p < CLS_P; p += blockDim.x) {
        int cp = lc[p];
        int rank = 0;
        for (int q = 0; q < CLS_P; q++) {
            int cq = lc[q];
            rank += (cq < cp) || (cq == cp && q < p);
        }
        if (rank < pcb)
            out_ids[c * pcb + rank] = ids[c * CLS_P + p];
    }
}

extern "C" void kernel_launch(void* const* d_in, const int* in_sizes, int n_in,
                              void* d_out, int out_size, void* d_ws, size_t ws_size,
                              hipStream_t stream) {
    const float* feats = (const float*)d_in[0];
    const int* ids = (const int*)d_in[1];
    int budget = out_size - N_TOT;
    int pcb = budget / NC;  // 200
    int* out = (int*)d_out;
    int* counts_out = out + NC * pcb;

    char* ws = (char*)d_ws;
    const size_t XHI_OFF = 0;
    const size_t XLO_OFF = XHI_OFF + (size_t)N_TOT * D * 2;          // 20.48 MB
    const size_t SQD_OFF = XLO_OFF + (size_t)N_TOT * D * 2;          // 40.96 MB
    const size_t SQF_OFF = SQD_OFF + (size_t)N_TOT * 8;
    const size_t ESCC_OFF = (SQF_OFF + (size_t)N_TOT * 4 + 63) & ~(size_t)63;
    const size_t ESCL_OFF = ESCC_OFF + 64;

    unsigned short* Xhi = (unsigned short*)(ws + XHI_OFF);
    unsigned short* Xlo = (unsigned short*)(ws + XLO_OFF);
    double* sqd = (double*)(ws + SQD_OFF);
    float* sqf = (float*)(ws + SQF_OFF);
    int* esc_cnt = (int*)(ws + ESCC_OFF);
    int2* esc_list = (int2*)(ws + ESCL_OFF);

    zero_kernel<<<(out_size + 255) / 256, 256, 0, stream>>>(out, out_size, esc_cnt);
    prep_kernel<<<N_TOT, 256, 0, stream>>>(feats, ids, Xhi, Xlo, sqd, sqf);
    dim3 grid((N_TOT + TM - 1) / TM, (N_TOT + TM - 1) / TM);
    count_kernel<<<grid, 256, 0, stream>>>(Xhi, Xlo, sqf, counts_out, esc_cnt, esc_list);
    escalate_kernel<<<2048, 256, 0, stream>>>(feats, ids, sqd, esc_cnt, esc_list, counts_out);
    sel_kernel<<<NC, 256, 0, stream>>>(counts_out, ids, out, pcb);
}

// Round 3
// 1393.925 us; speedup vs baseline: 4.3447x; 1.4180x over previous
//
#include <hip/hip_runtime.h>

#define N_TOT 10000
#define CLS_P 1000
#define NC 10
#define D 1024

#define TM 128          // block tile (i and j)
#define LDT 40          // LDS row stride in bf16 elems (32 + 8 pad) -> only free 2-way conflicts
#define DELTA 2e-5f
#define ESC_CAP (1 << 22)

typedef short bf16x8 __attribute__((ext_vector_type(8)));
typedef float f32x4 __attribute__((ext_vector_type(4)));

// ---------------- zero output + escalation counter ----------------
__global__ void zero_kernel(int* __restrict__ out, int n, int* __restrict__ esc_cnt) {
    int i = blockIdx.x * blockDim.x + threadIdx.x;
    if (i < n) out[i] = 0;
    if (i == 0) *esc_cnt = 0;
}

__device__ inline unsigned short f2bf_rne(float f) {
    unsigned int u = __float_as_uint(f);
    u += 0x7fffu + ((u >> 16) & 1u);
    return (unsigned short)(u >> 16);
}
__device__ inline float bf2f(unsigned short h) {
    return __uint_as_float(((unsigned int)h) << 16);
}

// ---------------- gather + bf16 hi/lo split + fp64 norms ----------------
__global__ void prep_kernel(const float* __restrict__ feats, const int* __restrict__ ids,
                            unsigned short* __restrict__ Xhi, unsigned short* __restrict__ Xlo,
                            double* __restrict__ sqd, float* __restrict__ sqf) {
    int row = blockIdx.x;
    int id = ids[row];
    const float4* rp = (const float4*)(feats + (size_t)id * D);
    float4 v = rp[threadIdx.x];  // 256 threads * 4 = 1024
    float f[4] = {v.x, v.y, v.z, v.w};
    ushort4 hv, lv;
    unsigned short* hp = &hv.x;
    unsigned short* lp = &lv.x;
    double s = 0.0;
    #pragma unroll
    for (int e = 0; e < 4; e++) {
        s += (double)f[e] * f[e];
        unsigned short hb = f2bf_rne(f[e]);
        float lo = f[e] - bf2f(hb);        // exact
        hp[e] = hb;
        lp[e] = f2bf_rne(lo);
    }
    *(ushort4*)(Xhi + (size_t)row * D + threadIdx.x * 4) = hv;
    *(ushort4*)(Xlo + (size_t)row * D + threadIdx.x * 4) = lv;

    #pragma unroll
    for (int off = 32; off > 0; off >>= 1)
        s += __shfl_down(s, off, 64);
    __shared__ double wsum[4];
    int lane = threadIdx.x & 63, wv = threadIdx.x >> 6;
    if (lane == 0) wsum[wv] = s;
    __syncthreads();
    if (threadIdx.x == 0) {
        double t = wsum[0] + wsum[1] + wsum[2] + wsum[3];
        sqd[row] = t;
        sqf[row] = (float)t;
    }
}

// ---------------- bf16-split MFMA pairwise count (upper-triangle tiles) ----------------
__launch_bounds__(256)
__global__ void count_kernel(const unsigned short* __restrict__ Xhi,
                             const unsigned short* __restrict__ Xlo,
                             const float* __restrict__ sqf,
                             int* __restrict__ counts,
                             int* __restrict__ esc_cnt, int2* __restrict__ esc_list) {
    const int ib = blockIdx.x * TM, jb = blockIdx.y * TM;
    if (jb < ib) return;  // symmetric: only upper triangle of tiles

    // skip tiles that are entirely same-class
    {
        int ci0 = ib / CLS_P, ci1 = (ib + TM - 1) / CLS_P;
        int cj0 = jb / CLS_P, cj1 = (jb + TM - 1) / CLS_P;
        if (ci0 == ci1 && cj0 == cj1 && ci0 == cj0) return;
    }

    __shared__ unsigned short Ah[TM * LDT], Al[TM * LDT], Bh[TM * LDT], Bl[TM * LDT];
    __shared__ int cred_i[TM], cred_j[TM];

    const int tid = threadIdx.x;
    const int lane = tid & 63, w = tid >> 6;
    const int wi = (w & 1) * 64, wj = (w >> 1) * 64;

    f32x4 acc[4][4];
    #pragma unroll
    for (int it = 0; it < 4; it++)
        #pragma unroll
        for (int jt = 0; jt < 4; jt++)
            acc[it][jt] = (f32x4){0.f, 0.f, 0.f, 0.f};

    const int quad = lane >> 4, col = lane & 15;
    const int kq8 = quad * 8;

    // staging mapping: thread handles rows (tid>>2) and 64+(tid>>2), k-quarter (tid&3)*8
    const int s_row0 = tid >> 2;
    const int s_kq = (tid & 3) * 8;
    const uint4 z4 = {0u, 0u, 0u, 0u};

    uint4 pf[2][4];  // [rep][Ah,Al,Bh,Bl] prefetch registers

    // prologue: load kc=0
    #pragma unroll
    for (int rep = 0; rep < 2; rep++) {
        int row = s_row0 + rep * 64;
        int gi = ib + row, gj = jb + row;
        size_t go = (size_t)s_kq;
        pf[rep][0] = (gi < N_TOT) ? *(const uint4*)(Xhi + (size_t)gi * D + go) : z4;
        pf[rep][1] = (gi < N_TOT) ? *(const uint4*)(Xlo + (size_t)gi * D + go) : z4;
        pf[rep][2] = (gj < N_TOT) ? *(const uint4*)(Xhi + (size_t)gj * D + go) : z4;
        pf[rep][3] = (gj < N_TOT) ? *(const uint4*)(Xlo + (size_t)gj * D + go) : z4;
    }
    #pragma unroll
    for (int rep = 0; rep < 2; rep++) {
        int row = s_row0 + rep * 64;
        *(uint4*)(Ah + row * LDT + s_kq) = pf[rep][0];
        *(uint4*)(Al + row * LDT + s_kq) = pf[rep][1];
        *(uint4*)(Bh + row * LDT + s_kq) = pf[rep][2];
        *(uint4*)(Bl + row * LDT + s_kq) = pf[rep][3];
    }
    __syncthreads();

    for (int kc = 0; kc < D / 32; kc++) {
        // prefetch next chunk into VGPRs (overlaps with MFMA below)
        if (kc + 1 < D / 32) {
            #pragma unroll
            for (int rep = 0; rep < 2; rep++) {
                int row = s_row0 + rep * 64;
                int gi = ib + row, gj = jb + row;
                size_t go = (size_t)(kc + 1) * 32 + s_kq;
                pf[rep][0] = (gi < N_TOT) ? *(const uint4*)(Xhi + (size_t)gi * D + go) : z4;
                pf[rep][1] = (gi < N_TOT) ? *(const uint4*)(Xlo + (size_t)gi * D + go) : z4;
                pf[rep][2] = (gj < N_TOT) ? *(const uint4*)(Xhi + (size_t)gj * D + go) : z4;
                pf[rep][3] = (gj < N_TOT) ? *(const uint4*)(Xlo + (size_t)gj * D + go) : z4;
            }
        }

        bf16x8 ah[4], al[4], bh[4], bl[4];
        #pragma unroll
        for (int t = 0; t < 4; t++) {
            ah[t] = *(const bf16x8*)(Ah + (wi + t * 16 + col) * LDT + kq8);
            al[t] = *(const bf16x8*)(Al + (wi + t * 16 + col) * LDT + kq8);
            bh[t] = *(const bf16x8*)(Bh + (wj + t * 16 + col) * LDT + kq8);
            bl[t] = *(const bf16x8*)(Bl + (wj + t * 16 + col) * LDT + kq8);
        }
        #pragma unroll
        for (int it = 0; it < 4; it++)
            #pragma unroll
            for (int jt = 0; jt < 4; jt++) {
                acc[it][jt] = __builtin_amdgcn_mfma_f32_16x16x32_bf16(ah[it], bh[jt], acc[it][jt], 0, 0, 0);
                acc[it][jt] = __builtin_amdgcn_mfma_f32_16x16x32_bf16(al[it], bh[jt], acc[it][jt], 0, 0, 0);
                acc[it][jt] = __builtin_amdgcn_mfma_f32_16x16x32_bf16(ah[it], bl[jt], acc[it][jt], 0, 0, 0);
            }

        __syncthreads();  // all ds_reads of this chunk done
        if (kc + 1 < D / 32) {
            #pragma unroll
            for (int rep = 0; rep < 2; rep++) {
                int row = s_row0 + rep * 64;
                *(uint4*)(Ah + row * LDT + s_kq) = pf[rep][0];
                *(uint4*)(Al + row * LDT + s_kq) = pf[rep][1];
                *(uint4*)(Bh + row * LDT + s_kq) = pf[rep][2];
                *(uint4*)(Bl + row * LDT + s_kq) = pf[rep][3];
            }
            __syncthreads();
        }
    }

    // ---------------- epilogue: threshold + escalate + symmetric reduce ----------------
    if (tid < TM) { cred_i[tid] = 0; cred_j[tid] = 0; }
    __syncthreads();

    const float thr_lo = 0.25f - DELTA;
    const float thr_hi = 0.25f + DELTA;
    const bool diag = (ib == jb);

    float sqj[4];
    int clsj[4], jv[4], jidx[4];
    #pragma unroll
    for (int jt = 0; jt < 4; jt++) {
        int j = jb + wj + jt * 16 + col;
        jidx[jt] = j;
        jv[jt] = (j < N_TOT);
        sqj[jt] = jv[jt] ? sqf[j] : 0.f;
        clsj[jt] = j / CLS_P;
    }

    int cj[4] = {0, 0, 0, 0};

    #pragma unroll
    for (int it = 0; it < 4; it++) {
        #pragma unroll
        for (int r = 0; r < 4; r++) {
            int irow = wi + it * 16 + quad * 4 + r;
            int i = ib + irow;
            bool iv = (i < N_TOT);
            float sqi = iv ? sqf[i] : 0.f;
            int clsi = i / CLS_P;
            int ci = 0;
            #pragma unroll
            for (int jt = 0; jt < 4; jt++) {
                int j = jidx[jt];
                if (iv && jv[jt] && clsj[jt] != clsi && (!diag || j > i)) {
                    float d2 = sqi + sqj[jt] - 2.0f * acc[it][jt][r];
                    if (d2 < thr_lo) {
                        ci++;
                        cj[jt]++;
                    } else if (d2 < thr_hi) {
                        int idx = atomicAdd(esc_cnt, 1);
                        if (idx < ESC_CAP) esc_list[idx] = make_int2(i, j);
                    }
                }
            }
            // reduce ci across the 16 cols of this quad (same i)
            ci += __shfl_xor(ci, 1, 64);
            ci += __shfl_xor(ci, 2, 64);
            ci += __shfl_xor(ci, 4, 64);
            ci += __shfl_xor(ci, 8, 64);
            if (col == 0 && ci) atomicAdd(&cred_i[irow], ci);
        }
    }
    // reduce cj across quads (same j, different i-rows)
    #pragma unroll
    for (int jt = 0; jt < 4; jt++) {
        int v = cj[jt];
        v += __shfl_xor(v, 16, 64);
        v += __shfl_xor(v, 32, 64);
        if (quad == 0 && v) atomicAdd(&cred_j[wj + jt * 16 + col], v);
    }
    __syncthreads();
    if (tid < TM) {
        int i = ib + tid;
        if (i < N_TOT && cred_i[tid]) atomicAdd(&counts[i], cred_i[tid]);
        int j = jb + tid;
        if (j < N_TOT && cred_j[tid]) atomicAdd(&counts[j], cred_j[tid]);
    }
}

// ---------------- fp64 exact recheck of borderline pairs (adds to BOTH ends) ----------------
__global__ void escalate_kernel(const float* __restrict__ feats, const int* __restrict__ ids,
                                const double* __restrict__ sqd,
                                const int* __restrict__ esc_cnt, const int2* __restrict__ esc_list,
                                int* __restrict__ counts) {
    int n = *esc_cnt;
    if (n > ESC_CAP) n = ESC_CAP;
    int lane = threadIdx.x & 63;
    int wglob = (blockIdx.x * blockDim.x + threadIdx.x) >> 6;
    int W = (gridDim.x * blockDim.x) >> 6;
    for (int p = wglob; p < n; p += W) {
        int2 pr = esc_list[p];
        const float* xi = feats + (size_t)ids[pr.x] * D;
        const float* xj = feats + (size_t)ids[pr.y] * D;
        double s = 0.0;
        int k0 = lane * 16;
        #pragma unroll
        for (int k = 0; k < 16; k += 4) {
            float4 a = *(const float4*)(xi + k0 + k);
            float4 b = *(const float4*)(xj + k0 + k);
            s += (double)a.x * b.x + (double)a.y * b.y + (double)a.z * b.z + (double)a.w * b.w;
        }
        #pragma unroll
        for (int off = 32; off > 0; off >>= 1)
            s += __shfl_down(s, off, 64);
        if (lane == 0) {
            double d2 = sqd[pr.x] + sqd[pr.y] - 2.0 * s;
            if (d2 < 0.25) {
                atomicAdd(&counts[pr.x], 1);
                atomicAdd(&counts[pr.y], 1);
            }
        }
    }
}

// ---------------- stable-argsort selection ----------------
__global__ void sel_kernel(const int* __restrict__ counts, const int* __restrict__ ids,
                           int* __restrict__ out_ids, int pcb) {
    int c = blockIdx.x;
    __shared__ int lc[CLS_P];
    for (int p = threadIdx.x; p < CLS_P; p += blockDim.x)
        lc[p] = counts[c * CLS_P + p];
    __syncthreads();
    for (int p = threadIdx.x; p < CLS_P; p += blockDim.x) {
        int cp = lc[p];
        int rank = 0;
        for (int q = 0; q < CLS_P; q++) {
            int cq = lc[q];
            rank += (cq < cp) || (cq == cp && q < p);
        }
        if (rank < pcb)
            out_ids[c * pcb + rank] = ids[c * CLS_P + p];
    }
}

extern "C" void kernel_launch(void* const* d_in, const int* in_sizes, int n_in,
                              void* d_out, int out_size, void* d_ws, size_t ws_size,
                              hipStream_t stream) {
    const float* feats = (const float*)d_in[0];
    const int* ids = (const int*)d_in[1];
    int budget = out_size - N_TOT;
    int pcb = budget / NC;  // 200
    int* out = (int*)d_out;
    int* counts_out = out + NC * pcb;

    char* ws = (char*)d_ws;
    const size_t XHI_OFF = 0;
    const size_t XLO_OFF = XHI_OFF + (size_t)N_TOT * D * 2;
    const size_t SQD_OFF = XLO_OFF + (size_t)N_TOT * D * 2;
    const size_t SQF_OFF = SQD_OFF + (size_t)N_TOT * 8;
    const size_t ESCC_OFF = (SQF_OFF + (size_t)N_TOT * 4 + 63) & ~(size_t)63;
    const size_t ESCL_OFF = ESCC_OFF + 64;

    unsigned short* Xhi = (unsigned short*)(ws + XHI_OFF);
    unsigned short* Xlo = (unsigned short*)(ws + XLO_OFF);
    double* sqd = (double*)(ws + SQD_OFF);
    float* sqf = (float*)(ws + SQF_OFF);
    int* esc_cnt = (int*)(ws + ESCC_OFF);
    int2* esc_list = (int2*)(ws + ESCL_OFF);

    zero_kernel<<<(out_size + 255) / 256, 256, 0, stream>>>(out, out_size, esc_cnt);
    prep_kernel<<<N_TOT, 256, 0, stream>>>(feats, ids, Xhi, Xlo, sqd, sqf);
    dim3 grid((N_TOT + TM - 1) / TM, (N_TOT + TM - 1) / TM);
    count_kernel<<<grid, 256, 0, stream>>>(Xhi, Xlo, sqf, counts_out, esc_cnt, esc_list);
    escalate_kernel<<<2048, 256, 0, stream>>>(feats, ids, sqd, esc_cnt, esc_list, counts_out);
    sel_kernel<<<NC, 256, 0, stream>>>(counts_out, ids, out, pcb);
}

// Round 4
// 634.699 us; speedup vs baseline: 9.5419x; 2.1962x over previous
//
#include <hip/hip_runtime.h>

#define N_TOT 10000
#define CLS_P 1000
#define NC 10
#define D 1024

#define TM 128          // block tile (i and j)
#define DELTA 5e-6f
#define ESC_CAP (1 << 22)
#define KCHUNKS (D / 32)

typedef short bf16x8 __attribute__((ext_vector_type(8)));
typedef float f32x4 __attribute__((ext_vector_type(4)));
typedef const __attribute__((address_space(1))) unsigned int* gptr_t;
typedef __attribute__((address_space(3))) unsigned int* lptr_t;

// ---------------- zero output + escalation counter ----------------
__global__ void zero_kernel(int* __restrict__ out, int n, int* __restrict__ esc_cnt) {
    int i = blockIdx.x * blockDim.x + threadIdx.x;
    if (i < n) out[i] = 0;
    if (i == 0) *esc_cnt = 0;
}

__device__ inline unsigned short f2bf_rne(float f) {
    unsigned int u = __float_as_uint(f);
    u += 0x7fffu + ((u >> 16) & 1u);
    return (unsigned short)(u >> 16);
}
__device__ inline float bf2f(unsigned short h) {
    return __uint_as_float(((unsigned int)h) << 16);
}

// ---------------- gather + bf16 hi/lo split + fp64 norms ----------------
__global__ void prep_kernel(const float* __restrict__ feats, const int* __restrict__ ids,
                            unsigned short* __restrict__ Xhi, unsigned short* __restrict__ Xlo,
                            double* __restrict__ sqd, float* __restrict__ sqf) {
    int row = blockIdx.x;
    int id = ids[row];
    const float4* rp = (const float4*)(feats + (size_t)id * D);
    float4 v = rp[threadIdx.x];  // 256 threads * 4 = 1024
    float f[4] = {v.x, v.y, v.z, v.w};
    ushort4 hv, lv;
    unsigned short* hp = &hv.x;
    unsigned short* lp = &lv.x;
    double s = 0.0;
    #pragma unroll
    for (int e = 0; e < 4; e++) {
        s += (double)f[e] * f[e];
        unsigned short hb = f2bf_rne(f[e]);
        float lo = f[e] - bf2f(hb);        // exact
        hp[e] = hb;
        lp[e] = f2bf_rne(lo);
    }
    *(ushort4*)(Xhi + (size_t)row * D + threadIdx.x * 4) = hv;
    *(ushort4*)(Xlo + (size_t)row * D + threadIdx.x * 4) = lv;

    #pragma unroll
    for (int off = 32; off > 0; off >>= 1)
        s += __shfl_down(s, off, 64);
    __shared__ double wsum[4];
    int lane = threadIdx.x & 63, wv = threadIdx.x >> 6;
    if (lane == 0) wsum[wv] = s;
    __syncthreads();
    if (threadIdx.x == 0) {
        double t = wsum[0] + wsum[1] + wsum[2] + wsum[3];
        sqd[row] = t;
        sqf[row] = (float)t;
    }
}

// ---------------- bf16-split MFMA pairwise count (upper-triangle, async dbuf) ----------------
__launch_bounds__(256)
__global__ void count_kernel(const unsigned short* __restrict__ Xhi,
                             const unsigned short* __restrict__ Xlo,
                             const float* __restrict__ sqf,
                             int* __restrict__ counts,
                             int* __restrict__ esc_cnt, int2* __restrict__ esc_list) {
    const int ib = blockIdx.x * TM, jb = blockIdx.y * TM;
    if (jb < ib) return;  // symmetric: only upper triangle of tiles

    // skip tiles that are entirely same-class
    {
        int ci0 = ib / CLS_P, ci1 = (ib + TM - 1) / CLS_P;
        int cj0 = jb / CLS_P, cj1 = (jb + TM - 1) / CLS_P;
        if (ci0 == ci1 && cj0 == cj1 && ci0 == cj0) return;
    }

    // 4 arrays (Ah,Al,Bh,Bl) x 2 buffers x 128 rows x 32 k-elems (swizzled k-slots)
    __shared__ unsigned short S[4 * 2 * 128 * 32];   // 64 KB
    __shared__ int cred_i[TM], cred_j[TM];

    const int tid = threadIdx.x;
    const int lane = tid & 63, w = tid >> 6;
    const int wi = (w & 1) * 64, wj = (w >> 1) * 64;
    const int quad = lane >> 4, col = lane & 15;

    // ---- staging setup: wave w stages array w ----
    const unsigned short* src_base = (w & 1) ? Xlo : Xhi;
    const int rowbase = (w < 2) ? ib : jb;
    unsigned short* arr = S + w * 8192;            // this wave's array (shorts)
    const int rl0 = lane >> 2;                     // row within 16-row call group
    const int s_idx = lane & 3;                    // dest k-slot
    // source k-quarter so that LDS [row][slot] holds source q with
    // slot = (q + row + (row>>2)) & 3   (note: row -> row+16 shifts by 20 ≡ 0 mod 4)
    const int qsw = (s_idx - rl0 - (rl0 >> 2)) & 3;

    #define STAGE(KC_, BUF_)                                                            \
        {                                                                               \
            _Pragma("unroll")                                                           \
            for (int b = 0; b < 8; b++) {                                               \
                int grow = rowbase + b * 16 + rl0;                                      \
                if (grow > N_TOT - 1) grow = N_TOT - 1;                                 \
                const unsigned short* sp =                                              \
                    src_base + (size_t)grow * D + (KC_) * 32 + qsw * 8;                 \
                lptr_t dst = (lptr_t)(arr + (BUF_) * 4096 + b * 512);                   \
                __builtin_amdgcn_global_load_lds((gptr_t)sp, dst, 16, 0, 0);            \
            }                                                                           \
        }

    f32x4 acc[4][4];
    #pragma unroll
    for (int it = 0; it < 4; it++)
        #pragma unroll
        for (int jt = 0; jt < 4; jt++)
            acc[it][jt] = (f32x4){0.f, 0.f, 0.f, 0.f};

    STAGE(0, 0);
    __syncthreads();   // vmcnt(0) drain + barrier: buf0 ready

    for (int kc = 0; kc < KCHUNKS; kc++) {
        const int buf = kc & 1;
        if (kc + 1 < KCHUNKS) STAGE(kc + 1, buf ^ 1);

        bf16x8 ah[4], al[4], bh[4], bl[4];
        #pragma unroll
        for (int t = 0; t < 4; t++) {
            int rA = wi + t * 16 + col;
            int sA = (quad + rA + (rA >> 2)) & 3;
            const unsigned short* pa = S + buf * 4096 + rA * 32 + sA * 8;
            ah[t] = *(const bf16x8*)(pa);
            al[t] = *(const bf16x8*)(pa + 8192);
            int rB = wj + t * 16 + col;
            int sB = (quad + rB + (rB >> 2)) & 3;
            const unsigned short* pb = S + 2 * 8192 + buf * 4096 + rB * 32 + sB * 8;
            bh[t] = *(const bf16x8*)(pb);
            bl[t] = *(const bf16x8*)(pb + 8192);
        }
        #pragma unroll
        for (int it = 0; it < 4; it++)
            #pragma unroll
            for (int jt = 0; jt < 4; jt++) {
                acc[it][jt] = __builtin_amdgcn_mfma_f32_16x16x32_bf16(ah[it], bh[jt], acc[it][jt], 0, 0, 0);
                acc[it][jt] = __builtin_amdgcn_mfma_f32_16x16x32_bf16(al[it], bh[jt], acc[it][jt], 0, 0, 0);
                acc[it][jt] = __builtin_amdgcn_mfma_f32_16x16x32_bf16(ah[it], bl[jt], acc[it][jt], 0, 0, 0);
            }

        __syncthreads();  // drains this iter's async loads + protects buffer reuse
    }

    // ---------------- epilogue: threshold + ballot-aggregated escalate + symmetric reduce ----------------
    if (tid < TM) { cred_i[tid] = 0; cred_j[tid] = 0; }
    __syncthreads();

    const float thr_lo = 0.25f - DELTA;
    const float thr_hi = 0.25f + DELTA;
    const bool diag = (ib == jb);

    float sqj[4];
    int clsj[4], jv[4], jidx[4];
    #pragma unroll
    for (int jt = 0; jt < 4; jt++) {
        int j = jb + wj + jt * 16 + col;
        jidx[jt] = j;
        jv[jt] = (j < N_TOT);
        sqj[jt] = jv[jt] ? sqf[j] : 0.f;
        clsj[jt] = j / CLS_P;
    }

    int cj[4] = {0, 0, 0, 0};

    #pragma unroll
    for (int it = 0; it < 4; it++) {
        #pragma unroll
        for (int r = 0; r < 4; r++) {
            int irow = wi + it * 16 + quad * 4 + r;
            int i = ib + irow;
            bool iv = (i < N_TOT);
            float sqi = iv ? sqf[i] : 0.f;
            int clsi = i / CLS_P;
            int ci = 0;
            #pragma unroll
            for (int jt = 0; jt < 4; jt++) {
                int j = jidx[jt];
                bool ok = iv && jv[jt] && (clsj[jt] != clsi) && (!diag || j > i);
                float d2 = sqi + sqj[jt] - 2.0f * acc[it][jt][r];
                bool in = ok && (d2 < thr_lo);
                bool esc = ok && !in && (d2 < thr_hi);
                ci += in ? 1 : 0;
                cj[jt] += in ? 1 : 0;
                unsigned long long m = __ballot(esc);
                if (m) {
                    int leader = __ffsll(m) - 1;
                    int cntw = __popcll(m);
                    int pre = __popcll(m & ((1ull << lane) - 1));
                    int base = 0;
                    if (lane == leader) base = atomicAdd(esc_cnt, cntw);
                    base = __shfl(base, leader, 64);
                    if (esc) {
                        int idx = base + pre;
                        if (idx < ESC_CAP) esc_list[idx] = make_int2(i, j);
                    }
                }
            }
            // reduce ci across the 16 cols of this quad (same i)
            ci += __shfl_xor(ci, 1, 64);
            ci += __shfl_xor(ci, 2, 64);
            ci += __shfl_xor(ci, 4, 64);
            ci += __shfl_xor(ci, 8, 64);
            if (col == 0 && ci) atomicAdd(&cred_i[irow], ci);
        }
    }
    // reduce cj across quads (same j, different i-rows)
    #pragma unroll
    for (int jt = 0; jt < 4; jt++) {
        int v = cj[jt];
        v += __shfl_xor(v, 16, 64);
        v += __shfl_xor(v, 32, 64);
        if (quad == 0 && v) atomicAdd(&cred_j[wj + jt * 16 + col], v);
    }
    __syncthreads();
    if (tid < TM) {
        int i = ib + tid;
        if (i < N_TOT && cred_i[tid]) atomicAdd(&counts[i], cred_i[tid]);
        int j = jb + tid;
        if (j < N_TOT && cred_j[tid]) atomicAdd(&counts[j], cred_j[tid]);
    }
}

// ---------------- fp64 exact recheck of borderline pairs (adds to BOTH ends) ----------------
__global__ void escalate_kernel(const float* __restrict__ feats, const int* __restrict__ ids,
                                const double* __restrict__ sqd,
                                const int* __restrict__ esc_cnt, const int2* __restrict__ esc_list,
                                int* __restrict__ counts) {
    int n = *esc_cnt;
    if (n > ESC_CAP) n = ESC_CAP;
    int lane = threadIdx.x & 63;
    int wglob = (blockIdx.x * blockDim.x + threadIdx.x) >> 6;
    int W = (gridDim.x * blockDim.x) >> 6;
    for (int p = wglob; p < n; p += W) {
        int2 pr = esc_list[p];
        const float* xi = feats + (size_t)ids[pr.x] * D;
        const float* xj = feats + (size_t)ids[pr.y] * D;
        double s = 0.0;
        int k0 = lane * 16;
        #pragma unroll
        for (int k = 0; k < 16; k += 4) {
            float4 a = *(const float4*)(xi + k0 + k);
            float4 b = *(const float4*)(xj + k0 + k);
            s += (double)a.x * b.x + (double)a.y * b.y + (double)a.z * b.z + (double)a.w * b.w;
        }
        #pragma unroll
        for (int off = 32; off > 0; off >>= 1)
            s += __shfl_down(s, off, 64);
        if (lane == 0) {
            double d2 = sqd[pr.x] + sqd[pr.y] - 2.0 * s;
            if (d2 < 0.25) {
                atomicAdd(&counts[pr.x], 1);
                atomicAdd(&counts[pr.y], 1);
            }
        }
    }
}

// ---------------- stable-argsort selection ----------------
__global__ void sel_kernel(const int* __restrict__ counts, const int* __restrict__ ids,
                           int* __restrict__ out_ids, int pcb) {
    int c = blockIdx.x;
    __shared__ int lc[CLS_P];
    for (int p = threadIdx.x; p < CLS_P; p += blockDim.x)
        lc[p] = counts[c * CLS_P + p];
    __syncthreads();
    for (int p = threadIdx.x; p < CLS_P; p += blockDim.x) {
        int cp = lc[p];
        int rank = 0;
        for (int q = 0; q < CLS_P; q++) {
            int cq = lc[q];
            rank += (cq < cp) || (cq == cp && q < p);
        }
        if (rank < pcb)
            out_ids[c * pcb + rank] = ids[c * CLS_P + p];
    }
}

extern "C" void kernel_launch(void* const* d_in, const int* in_sizes, int n_in,
                              void* d_out, int out_size, void* d_ws, size_t ws_size,
                              hipStream_t stream) {
    const float* feats = (const float*)d_in[0];
    const int* ids = (const int*)d_in[1];
    int budget = out_size - N_TOT;
    int pcb = budget / NC;  // 200
    int* out = (int*)d_out;
    int* counts_out = out + NC * pcb;

    char* ws = (char*)d_ws;
    const size_t XHI_OFF = 0;
    const size_t XLO_OFF = XHI_OFF + (size_t)N_TOT * D * 2;
    const size_t SQD_OFF = XLO_OFF + (size_t)N_TOT * D * 2;
    const size_t SQF_OFF = SQD_OFF + (size_t)N_TOT * 8;
    const size_t ESCC_OFF = (SQF_OFF + (size_t)N_TOT * 4 + 63) & ~(size_t)63;
    const size_t ESCL_OFF = ESCC_OFF + 64;

    unsigned short* Xhi = (unsigned short*)(ws + XHI_OFF);
    unsigned short* Xlo = (unsigned short*)(ws + XLO_OFF);
    double* sqd = (double*)(ws + SQD_OFF);
    float* sqf = (float*)(ws + SQF_OFF);
    int* esc_cnt = (int*)(ws + ESCC_OFF);
    int2* esc_list = (int2*)(ws + ESCL_OFF);

    zero_kernel<<<(out_size + 255) / 256, 256, 0, stream>>>(out, out_size, esc_cnt);
    prep_kernel<<<N_TOT, 256, 0, stream>>>(feats, ids, Xhi, Xlo, sqd, sqf);
    dim3 grid((N_TOT + TM - 1) / TM, (N_TOT + TM - 1) / TM);
    count_kernel<<<grid, 256, 0, stream>>>(Xhi, Xlo, sqf, counts_out, esc_cnt, esc_list);
    escalate_kernel<<<2048, 256, 0, stream>>>(feats, ids, sqd, esc_cnt, esc_list, counts_out);
    sel_kernel<<<NC, 256, 0, stream>>>(counts_out, ids, out, pcb);
}